// Round 7
// baseline (941.082 us; speedup 1.0000x reference)
//
#include <hip/hip_runtime.h>

typedef __attribute__((ext_vector_type(8))) short short8;
typedef __attribute__((ext_vector_type(4))) short short4v;
typedef __attribute__((ext_vector_type(4))) float f32x4;

__device__ __forceinline__ unsigned short f2bf(float f) {
  unsigned int u = __float_as_uint(f);
  u += 0x7fffu + ((u >> 16) & 1u);   // RNE round to bf16
  return (unsigned short)(u >> 16);
}
__device__ __forceinline__ float bf2f(unsigned short u) {
  return __uint_as_float(((unsigned int)u) << 16);
}
__device__ __forceinline__ float sigm(float x) { return 1.f / (1.f + expf(-x)); }

typedef const __attribute__((address_space(1))) unsigned int GUI;
typedef __attribute__((address_space(3))) unsigned int LUI;
__device__ __forceinline__ void g2l16(const void* g, void* l) {
  __builtin_amdgcn_global_load_lds((GUI*)g, (LUI*)l, 16, 0, 0);
}
template<int N> __device__ __forceinline__ void waitvm() {
  if constexpr (N == 0)       asm volatile("s_waitcnt vmcnt(0)" ::: "memory");
  else if constexpr (N == 11) asm volatile("s_waitcnt vmcnt(11)" ::: "memory");
  else                        asm volatile("s_waitcnt vmcnt(15)" ::: "memory");
}

// ---------------------------------------------------------------------------
// Pipelined skinny GEMM: 112(M) x 64(N) per block, chunk = 128 K.
// X (28KB) and W staged to ping-pong LDS via global_load_lds; raw s_barrier +
// counted vmcnt keeps next chunk's loads in flight across MFMA.
// gemm_pb: bf16 W (LDS 2x(28+16)KB). gemm_pf: f32 W (LDS 2x(28+32)KB).
// OUTF32: direct f32 out (+bias, ldc, rowLim); else bf16 out (+z*slotStride).
// ---------------------------------------------------------------------------
template<int NCH, bool OUTF32>
__global__ __launch_bounds__(256) void gemm_pb(
    const unsigned short* __restrict__ X, int ldx,
    const unsigned short* __restrict__ W, int ldw, int N,
    void* __restrict__ Cv, long long slotStride,
    const float* __restrict__ bias, long long ldc, int rowLim)
{
  __shared__ __align__(16) char smem[2 * 28672 + 2 * 16384];
  const int tid = threadIdx.x, lane = tid & 63, wv = tid >> 6;
  const int l16 = lane & 15, kg = (lane >> 4) * 8;
  const int mbase = blockIdx.y * 112;
  const int ncol = blockIdx.x * 64 + wv * 16 + l16;
  const int nrow = (ncol < N) ? ncol : (N - 1);
  const long long kbase = (long long)blockIdx.z * (NCH * 128);

  const unsigned short* xb = X + (size_t)(mbase + l16) * ldx + kbase + kg;
  const unsigned short* wb = W + (size_t)nrow * ldw + kbase + kg;
  const size_t xrow16 = (size_t)16 * ldx;

  auto stage = [&](int nb, int ch) {
#pragma unroll
    for (int i = 0; i < 7; ++i) {
      const int f = wv + i * 4, mt = f >> 2, ks = f & 3;
      g2l16(xb + (size_t)mt * xrow16 + ch * 128 + ks * 32,
            smem + nb * 28672 + f * 1024);
    }
#pragma unroll
    for (int ks = 0; ks < 4; ++ks)
      g2l16(wb + ch * 128 + ks * 32,
            smem + 57344 + nb * 16384 + (wv * 4 + ks) * 1024);
  };

  f32x4 acc[7];
#pragma unroll
  for (int i = 0; i < 7; ++i) acc[i] = (f32x4){0.f, 0.f, 0.f, 0.f};

  stage(0, 0);
#pragma unroll
  for (int t = 0; t < NCH; ++t) {
    if (t + 1 < NCH) { stage((t + 1) & 1, t + 1); waitvm<11>(); }
    else waitvm<0>();
    __builtin_amdgcn_s_barrier();
    __builtin_amdgcn_sched_barrier(0);
    const char* xs  = smem + (t & 1) * 28672;
    const char* wsm = smem + 57344 + (t & 1) * 16384;
#pragma unroll
    for (int ks = 0; ks < 4; ++ks) {
      short8 w = *(const short8*)(wsm + (wv * 4 + ks) * 1024 + lane * 16);
#pragma unroll
      for (int mt = 0; mt < 7; ++mt) {
        short8 a = *(const short8*)(xs + (mt * 4 + ks) * 1024 + lane * 16);
        acc[mt] = __builtin_amdgcn_mfma_f32_16x16x32_bf16(a, w, acc[mt], 0, 0, 0);
      }
    }
    __builtin_amdgcn_sched_barrier(0);
    __builtin_amdgcn_s_barrier();
  }

  if (ncol < N) {
    const int r0 = (lane >> 4) * 4;
    if constexpr (OUTF32) {
      float* outF = (float*)Cv;
      const float bv = bias ? bias[ncol] : 0.f;
#pragma unroll
      for (int mt = 0; mt < 7; ++mt)
#pragma unroll
        for (int r = 0; r < 4; ++r) {
          const int row = mbase + mt * 16 + r0 + r;
          if (row < rowLim) outF[(size_t)row * ldc + ncol] = acc[mt][r] + bv;
        }
    } else {
      unsigned short* C = (unsigned short*)Cv + (long long)blockIdx.z * slotStride;
#pragma unroll
      for (int mt = 0; mt < 7; ++mt)
#pragma unroll
        for (int r = 0; r < 4; ++r)
          C[(size_t)(mbase + mt * 16 + r0 + r) * N + ncol] = f2bf(acc[mt][r]);
    }
  }
}

template<int NCH, bool OUTF32>
__global__ __launch_bounds__(256) void gemm_pf(
    const unsigned short* __restrict__ X, int ldx,
    const float* __restrict__ W, int ldw, int N,
    void* __restrict__ Cv, long long slotStride,
    const float* __restrict__ bias, long long ldc, int rowLim)
{
  __shared__ __align__(16) char smem[2 * 28672 + 2 * 32768];
  const int tid = threadIdx.x, lane = tid & 63, wv = tid >> 6;
  const int l16 = lane & 15, kg = (lane >> 4) * 8;
  const int mbase = blockIdx.y * 112;
  const int ncol = blockIdx.x * 64 + wv * 16 + l16;
  const int nrow = (ncol < N) ? ncol : (N - 1);
  const long long kbase = (long long)blockIdx.z * (NCH * 128);

  const unsigned short* xb = X + (size_t)(mbase + l16) * ldx + kbase + kg;
  const float* wb = W + (size_t)nrow * ldw + kbase + kg;
  const size_t xrow16 = (size_t)16 * ldx;

  auto stage = [&](int nb, int ch) {
#pragma unroll
    for (int i = 0; i < 7; ++i) {
      const int f = wv + i * 4, mt = f >> 2, ks = f & 3;
      g2l16(xb + (size_t)mt * xrow16 + ch * 128 + ks * 32,
            smem + nb * 28672 + f * 1024);
    }
#pragma unroll
    for (int ks = 0; ks < 4; ++ks)
#pragma unroll
      for (int h = 0; h < 2; ++h)
        g2l16(wb + ch * 128 + ks * 32 + h * 4,
              smem + 57344 + nb * 32768 + ((wv * 4 + ks) * 2 + h) * 1024);
  };

  f32x4 acc[7];
#pragma unroll
  for (int i = 0; i < 7; ++i) acc[i] = (f32x4){0.f, 0.f, 0.f, 0.f};

  stage(0, 0);
#pragma unroll
  for (int t = 0; t < NCH; ++t) {
    if (t + 1 < NCH) { stage((t + 1) & 1, t + 1); waitvm<15>(); }
    else waitvm<0>();
    __builtin_amdgcn_s_barrier();
    __builtin_amdgcn_sched_barrier(0);
    const char* xs  = smem + (t & 1) * 28672;
    const char* wsm = smem + 57344 + (t & 1) * 32768;
#pragma unroll
    for (int ks = 0; ks < 4; ++ks) {
      float4 wa = *(const float4*)(wsm + ((wv * 4 + ks) * 2 + 0) * 1024 + lane * 16);
      float4 wc = *(const float4*)(wsm + ((wv * 4 + ks) * 2 + 1) * 1024 + lane * 16);
      short8 w;
      w[0] = (short)f2bf(wa.x); w[1] = (short)f2bf(wa.y);
      w[2] = (short)f2bf(wa.z); w[3] = (short)f2bf(wa.w);
      w[4] = (short)f2bf(wc.x); w[5] = (short)f2bf(wc.y);
      w[6] = (short)f2bf(wc.z); w[7] = (short)f2bf(wc.w);
#pragma unroll
      for (int mt = 0; mt < 7; ++mt) {
        short8 a = *(const short8*)(xs + (mt * 4 + ks) * 1024 + lane * 16);
        acc[mt] = __builtin_amdgcn_mfma_f32_16x16x32_bf16(a, w, acc[mt], 0, 0, 0);
      }
    }
    __builtin_amdgcn_sched_barrier(0);
    __builtin_amdgcn_s_barrier();
  }

  if (ncol < N) {
    const int r0 = (lane >> 4) * 4;
    if constexpr (OUTF32) {
      float* outF = (float*)Cv;
      const float bv = bias ? bias[ncol] : 0.f;
#pragma unroll
      for (int mt = 0; mt < 7; ++mt)
#pragma unroll
        for (int r = 0; r < 4; ++r) {
          const int row = mbase + mt * 16 + r0 + r;
          if (row < rowLim) outF[(size_t)row * ldc + ncol] = acc[mt][r] + bv;
        }
    } else {
      unsigned short* C = (unsigned short*)Cv + (long long)blockIdx.z * slotStride;
#pragma unroll
      for (int mt = 0; mt < 7; ++mt)
#pragma unroll
        for (int r = 0; r < 4; ++r)
          C[(size_t)(mbase + mt * 16 + r0 + r) * N + ncol] = f2bf(acc[mt][r]);
    }
  }
}

// cat GEMM: W = packed [W_fc1;W_dec] bf16 (10512x1024). cols<10000 -> f32 out
// (+bias) to preds1 slab; cols>=10000 -> bf16 padec.
__global__ __launch_bounds__(256) void gemm_pcat(
    const unsigned short* __restrict__ X,
    const unsigned short* __restrict__ W,
    float* __restrict__ outF, const float* __restrict__ bias,
    unsigned short* __restrict__ padec)
{
  __shared__ __align__(16) char smem[2 * 28672 + 2 * 16384];
  const int tid = threadIdx.x, lane = tid & 63, wv = tid >> 6;
  const int l16 = lane & 15, kg = (lane >> 4) * 8;
  const int ncol0 = blockIdx.x * 64 + wv * 16 + l16;
  const int nrow = (ncol0 < 10512) ? ncol0 : 10511;

  const unsigned short* xb = X + (size_t)l16 * 1024 + kg;
  const unsigned short* wb = W + (size_t)nrow * 1024 + kg;
  const size_t xrow16 = (size_t)16 * 1024;

  auto stage = [&](int nb, int ch) {
#pragma unroll
    for (int i = 0; i < 7; ++i) {
      const int f = wv + i * 4, mt = f >> 2, ks = f & 3;
      g2l16(xb + (size_t)mt * xrow16 + ch * 128 + ks * 32,
            smem + nb * 28672 + f * 1024);
    }
#pragma unroll
    for (int ks = 0; ks < 4; ++ks)
      g2l16(wb + ch * 128 + ks * 32,
            smem + 57344 + nb * 16384 + (wv * 4 + ks) * 1024);
  };

  f32x4 acc[7];
#pragma unroll
  for (int i = 0; i < 7; ++i) acc[i] = (f32x4){0.f, 0.f, 0.f, 0.f};

  stage(0, 0);
#pragma unroll
  for (int t = 0; t < 8; ++t) {
    if (t + 1 < 8) { stage((t + 1) & 1, t + 1); waitvm<11>(); }
    else waitvm<0>();
    __builtin_amdgcn_s_barrier();
    __builtin_amdgcn_sched_barrier(0);
    const char* xs  = smem + (t & 1) * 28672;
    const char* wsm = smem + 57344 + (t & 1) * 16384;
#pragma unroll
    for (int ks = 0; ks < 4; ++ks) {
      short8 w = *(const short8*)(wsm + (wv * 4 + ks) * 1024 + lane * 16);
#pragma unroll
      for (int mt = 0; mt < 7; ++mt) {
        short8 a = *(const short8*)(xs + (mt * 4 + ks) * 1024 + lane * 16);
        acc[mt] = __builtin_amdgcn_mfma_f32_16x16x32_bf16(a, w, acc[mt], 0, 0, 0);
      }
    }
    __builtin_amdgcn_sched_barrier(0);
    __builtin_amdgcn_s_barrier();
  }

  const int r0 = (lane >> 4) * 4;
  if (ncol0 < 10000) {
    const float bv = bias[ncol0];
#pragma unroll
    for (int mt = 0; mt < 7; ++mt)
#pragma unroll
      for (int r = 0; r < 4; ++r) {
        const int row = mt * 16 + r0 + r;
        if (row < 100) outF[(size_t)row * 50000 + ncol0] = acc[mt][r] + bv;
      }
  } else if (ncol0 < 10512) {
#pragma unroll
    for (int mt = 0; mt < 7; ++mt)
#pragma unroll
      for (int r = 0; r < 4; ++r)
        padec[(size_t)(mt * 16 + r0 + r) * 512 + (ncol0 - 10000)] = f2bf(acc[mt][r]);
  }
}

// -------- fused weight pack: Wg1, Wg2, Wcat=[Wfc1;Wdec], Wfcb, Wtopb --------
__global__ __launch_bounds__(256) void k_pack_all(
    const float* __restrict__ Wih1, const float* __restrict__ Whh1,
    const float* __restrict__ Wih2, const float* __restrict__ Whh2,
    const float* __restrict__ Wfc1, const float* __restrict__ Wdec,
    const float* __restrict__ Wfc,  const float* __restrict__ Wtop,
    unsigned short* __restrict__ Wg1, unsigned short* __restrict__ Wg2,
    unsigned short* __restrict__ Wcat, unsigned short* __restrict__ Wfcb,
    unsigned short* __restrict__ Wtopb)
{
  int i = blockIdx.x * 256 + threadIdx.x;            // 13,705,216 vec4 total
  float4 v; unsigned short* dst; long long di;
  if (i < 2097152) {                                  // Wg1 = [Wih1.h2 | Whh1]
    int row = i >> 9, c4 = i & 511;
    const float* s = (c4 < 256) ? Wih1 + (size_t)row * 6144 + c4 * 4
                                : Whh1 + (size_t)row * 1024 + (c4 - 256) * 4;
    v = *(const float4*)s; dst = Wg1; di = i;
  } else if (i < 8388608) {                           // Wg2 = [Wih2 | Whh2]
    int j = i - 2097152; int row = j / 1536, c4 = j - row * 1536;
    const float* s = (c4 < 1280) ? Wih2 + (size_t)row * 5120 + c4 * 4
                                 : Whh2 + (size_t)row * 1024 + (c4 - 1280) * 4;
    v = *(const float4*)s; dst = Wg2; di = j;
  } else if (i < 11079680) {                          // Wcat = [Wfc1 ; Wdec]
    int j = i - 8388608; int row = j >> 8, c4 = j & 255;
    const float* s = (row < 10000) ? Wfc1 + (size_t)row * 1024 + c4 * 4
                                   : Wdec + (size_t)(row - 10000) * 1024 + c4 * 4;
    v = *(const float4*)s; dst = Wcat; di = j;
  } else if (i < 13639680) { int j = i - 11079680; v = ((const float4*)Wfc)[j]; dst = Wfcb; di = j; }
  else {                                              // Wtopb 512x512, K-pad
    int j = i - 13639680; if (j >= 65536) return;
    int n = j >> 7, c4 = j & 127;
    v = (c4 < 125) ? *(const float4*)(Wtop + (size_t)n * 500 + c4 * 4)
                   : (float4){0.f, 0.f, 0.f, 0.f};
    dst = Wtopb; di = j;
  }
  short4v o; o[0] = (short)f2bf(v.x); o[1] = (short)f2bf(v.y);
  o[2] = (short)f2bf(v.z); o[3] = (short)f2bf(v.w);
  ((short4v*)dst)[di] = o;
}

// --------------------------- helper kernels ------------------------
__global__ __launch_bounds__(256) void k_ximg2(const float* __restrict__ img,
    unsigned short* __restrict__ Ximg, unsigned short* __restrict__ Xmean) {
  int idx = blockIdx.x * 256 + threadIdx.x;          // 100*4096
  int b = idx >> 12, f = idx & 4095;
  float s = 0.f;
#pragma unroll
  for (int r = 0; r < 15; ++r) {
    float v = img[((size_t)(b * 15 + r) << 12) + f];
    s += v;
    Ximg[((size_t)(b * 15 + r) << 12) + f] = f2bf(v);
  }
  Xmean[((size_t)b << 12) + f] = f2bf(s * (1.f / 15.f));
}

__global__ __launch_bounds__(256) void k_reduce(const unsigned short* __restrict__ P,
    long long ss, int nslots, const float* __restrict__ bias, int colmask,
    float* __restrict__ out, int total) {
  int idx = blockIdx.x * 256 + threadIdx.x;
  if (idx >= total) return;
  float s = bias ? bias[idx & colmask] : 0.f;
  for (int sl = 0; sl < nslots; ++sl) s += bf2f(P[(size_t)sl * ss + idx]);
  out[idx] = s;
}

// conv: fused lin split-K reduce (2 bf16 slots) + direct bf16 Xtop write
__global__ __launch_bounds__(512) void k_conv(const unsigned short* __restrict__ px,
    const float* __restrict__ blt, const float* __restrict__ cw,
    const float* __restrict__ cb, unsigned short* __restrict__ Xtop) {
  int b = blockIdx.x;
  __shared__ float L[15 * 1024];
  for (int i = threadIdx.x; i < 15 * 1024; i += 512) {
    float s = blt[i & 1023];
#pragma unroll
    for (int sl = 0; sl < 2; ++sl)
      s += bf2f(px[(size_t)sl * 1605632 + (size_t)b * 15360 + i]);
    L[i] = s;
  }
  __syncthreads();
  for (int idx = threadIdx.x; idx < 2500; idx += 512) {
    int tt = idx / 500, w = idx - tt * 500;
    float s = cb[tt];
    for (int kh = 0; kh < 15; ++kh) {
      const float* lr = &L[kh * 1024 + 2 * w];
      const float* wr = &cw[(tt * 15 + kh) * 26];
#pragma unroll
      for (int kw = 0; kw < 26; ++kw) s += lr[kw] * wr[kw];
    }
    Xtop[((size_t)(b * 5 + tt)) * 512 + w] = f2bf(s);
  }
}

// word gather + caps/lens outputs, one dispatch
__global__ __launch_bounds__(256) void k_gw(const int* __restrict__ caps,
    const int* __restrict__ lens, const float* __restrict__ emb,
    unsigned short* __restrict__ Xemb, float* __restrict__ out2,
    float* __restrict__ out3) {
  int idx = blockIdx.x * 256 + threadIdx.x;          // 560*1024
  int bt = idx >> 10, e = idx & 1023;
  if (bt < 500) {
    int w = caps[bt * 52 + lens[bt] - 1];
    Xemb[idx] = f2bf(emb[(size_t)w * 1024 + e]);
  } else if (bt < 560) Xemb[idx] = 0;
  if (idx < 26000) out2[idx] = (float)caps[idx];
  if (idx < 500) out3[idx] = (float)(lens[idx] - 1);
}

__global__ __launch_bounds__(256) void k_gbase1(const unsigned short* __restrict__ P,
    const float* __restrict__ bih, const float* __restrict__ bhh,
    float* __restrict__ gb) {
  int idx = blockIdx.x * 256 + threadIdx.x;          // 112*4096
  int m = idx >> 12, n = idx & 4095;
  float s = bih[n] + bhh[n];
#pragma unroll
  for (int sl = 0; sl < 4; ++sl) s += bf2f(P[((size_t)sl * 112 + m) * 4096 + n]);
  gb[idx] = s;
}

// ------------------------------ per-step kernels ---------------------------
__global__ __launch_bounds__(256) void k_lstm1(const unsigned short* __restrict__ P,
    const float* __restrict__ gb1, const float* __restrict__ gemb, int t,
    float* __restrict__ c1, unsigned short* __restrict__ Xh1,
    unsigned short* __restrict__ X1, unsigned short* __restrict__ X2) {
  int idx = blockIdx.x * 256 + threadIdx.x;          // 100*1024
  int b = idx >> 10, j = idx & 1023;
  float g[4];
#pragma unroll
  for (int x = 0; x < 4; ++x) {
    int col = (x << 10) + j;
    float s = gb1[b * 4096 + col] + gemb[((size_t)b * 5 + t) * 4096 + col];
#pragma unroll
    for (int sl = 0; sl < 4; ++sl) s += bf2f(P[((size_t)sl * 112 + b) * 4096 + col]);
    g[x] = s;
  }
  float c = sigm(g[1]) * c1[idx] + sigm(g[0]) * tanhf(g[2]);
  float h = sigm(g[3]) * tanhf(c);
  c1[idx] = c;
  unsigned short hb = f2bf(h);
  Xh1[idx] = hb;
  X1[b * 2048 + 1024 + j] = hb;
  X2[(size_t)b * 6144 + 4096 + j] = hb;
}

__global__ __launch_bounds__(256) void k_attawe(const float* __restrict__ att1,
    const unsigned short* __restrict__ padec, const float* __restrict__ bdec,
    const float* __restrict__ btop, const unsigned short* __restrict__ ttopb,
    const float* __restrict__ wfull, int t,
    const unsigned short* __restrict__ Ximg, unsigned short* __restrict__ X2) {
  int b = blockIdx.x;
  int tid = threadIdx.x;
  int r = tid & 15, ch = tid >> 4;                   // 15 regions x 16 chunks
  __shared__ float sp[16][17];
  __shared__ float al[16];
  float s = 0.f;
  if (r < 15) {
    const float* a1 = att1 + ((size_t)b * 15 + r) * 512;
    const unsigned short* tp = ttopb + ((size_t)b * 5 + t) * 512;
#pragma unroll
    for (int j = 0; j < 32; ++j) {
      int n = ch * 32 + j;
      float ad = bdec[n] + btop[n] + bf2f(padec[(size_t)b * 512 + n]);
      float v = a1[n] + ad + bf2f(tp[n]);
      s += fmaxf(v, 0.f) * wfull[n];
    }
  }
  sp[r][ch] = s;
  __syncthreads();
  if (tid == 0) {
    float sc[15];
    float m = -1e30f;
    for (int rr = 0; rr < 15; ++rr) {
      float x = 0.f;
      for (int cc = 0; cc < 16; ++cc) x += sp[rr][cc];
      sc[rr] = x; m = fmaxf(m, x);
    }
    float sum = 0.f;
    for (int rr = 0; rr < 15; ++rr) { sc[rr] = expf(sc[rr] - m); sum += sc[rr]; }
    float inv = 1.f / sum;
    for (int rr = 0; rr < 15; ++rr) al[rr] = sc[rr] * inv;
  }
  __syncthreads();
  for (int f = tid; f < 4096; f += 256) {
    float s2 = 0.f;
#pragma unroll
    for (int rr = 0; rr < 15; ++rr)
      s2 += al[rr] * bf2f(Ximg[((size_t)b * 15 + rr) * 4096 + f]);
    X2[(size_t)b * 6144 + f] = f2bf(s2);
  }
}

__global__ __launch_bounds__(256) void k_lstm2(const unsigned short* __restrict__ P,
    const float* __restrict__ bih, const float* __restrict__ bhh,
    float* __restrict__ c2, unsigned short* __restrict__ Xh2,
    unsigned short* __restrict__ X1, unsigned short* __restrict__ X2) {
  int idx = blockIdx.x * 256 + threadIdx.x;          // 100*1024
  int b = idx >> 10, j = idx & 1023;
  float g[4];
#pragma unroll
  for (int x = 0; x < 4; ++x) {
    int col = (x << 10) + j;
    float s = bih[col] + bhh[col];
#pragma unroll
    for (int sl = 0; sl < 6; ++sl) s += bf2f(P[((size_t)sl * 112 + b) * 4096 + col]);
    g[x] = s;
  }
  float c = sigm(g[1]) * c2[idx] + sigm(g[0]) * tanhf(g[2]);
  float h = sigm(g[3]) * tanhf(c);
  c2[idx] = c;
  unsigned short hb = f2bf(h);
  Xh2[idx] = hb;
  X1[b * 2048 + j] = hb;
  X2[(size_t)b * 6144 + 5120 + j] = hb;
}

// ---------------------------------------------------------------------------
extern "C" void kernel_launch(void* const* d_in, const int* in_sizes, int n_in,
                              void* d_out, int out_size, void* d_ws, size_t ws_size,
                              hipStream_t stream) {
  (void)in_sizes; (void)n_in; (void)out_size;
  const float* imgf  = (const float*)d_in[0];
  const int*   caps  = (const int*)d_in[1];
  const int*   lens  = (const int*)d_in[2];
  const float* W_lt  = (const float*)d_in[3];
  const float* b_lt  = (const float*)d_in[4];
  const float* convw = (const float*)d_in[5];
  const float* convb = (const float*)d_in[6];
  const float* W_feat = (const float*)d_in[7];
  const float* b_feat = (const float*)d_in[8];
  const float* W_dec = (const float*)d_in[9];
  const float* b_dec = (const float*)d_in[10];
  const float* W_top = (const float*)d_in[11];
  const float* b_top = (const float*)d_in[12];
  const float* W_full = (const float*)d_in[13];
  const float* b_full = (const float*)d_in[14];  (void)b_full;  // cancels in softmax
  const float* emb   = (const float*)d_in[15];
  const float* W_ih1 = (const float*)d_in[16];
  const float* W_hh1 = (const float*)d_in[17];
  const float* b_ih1 = (const float*)d_in[18];
  const float* b_hh1 = (const float*)d_in[19];
  const float* W_ih2 = (const float*)d_in[20];
  const float* W_hh2 = (const float*)d_in[21];
  const float* b_ih2 = (const float*)d_in[22];
  const float* b_hh2 = (const float*)d_in[23];
  const float* W_fc1 = (const float*)d_in[24];
  const float* b_fc1 = (const float*)d_in[25];
  const float* W_fc  = (const float*)d_in[26];
  const float* b_fc  = (const float*)d_in[27];
  float* out = (float*)d_out;

  char* ws = (char*)d_ws;
  size_t off = 0;
  auto alloc = [&](size_t bytes) -> size_t {
    size_t o = off; off = (off + bytes + 255) & ~(size_t)255; return o;
  };
  const size_t oZERO  = off;                         // ---- zero block start
  const size_t oXimg  = alloc(1568ull * 4096 * 2);
  const size_t oXmean = alloc(112ull * 4096 * 2);
  const size_t oX1    = alloc(112ull * 2048 * 2);    // [h2 | h1] bf16
  const size_t oX2    = alloc(112ull * 6144 * 2);    // [awe | h1 | h2prev] bf16
  const size_t oXh1   = alloc(112ull * 1024 * 2);
  const size_t oXh2   = alloc(112ull * 1024 * 2);
  const size_t oc1    = alloc(100ull * 1024 * 4);
  const size_t oc2    = alloc(100ull * 1024 * 4);
  const size_t oXtop  = alloc(560ull * 512 * 2);
  const size_t zeroBytes = off - oZERO;              // ---- zero block end
  const size_t oXemb  = alloc(560ull * 1024 * 2);
  const size_t oTtopb = alloc(560ull * 512 * 2);
  const size_t oatt1  = alloc(1568ull * 512 * 4);
  const size_t ogb1   = alloc(112ull * 4096 * 4);
  const size_t ogemb  = alloc(560ull * 4096 * 4);
  const size_t opg    = alloc(6ull * 112 * 4096 * 2);   // gate partials (bf16)
  const size_t opx    = alloc(2ull * 1568 * 1024 * 2);  // phase-A partials (bf16)
  const size_t opadec = alloc(112ull * 512 * 2);
  const size_t oWg1   = alloc(4096ull * 2048 * 2);      // [Wih1.h2 | Whh1]
  const size_t oWg2   = alloc(4096ull * 6144 * 2);      // [Wih2 | Whh2]
  const size_t oWcat  = alloc(10512ull * 1024 * 2);     // [W_fc1 ; W_dec]
  const size_t oWfcb  = alloc(10000ull * 1024 * 2);
  const size_t oWtopb = alloc(512ull * 512 * 2);
  if (ws_size < off) return;  // insufficient scratch — loud fail

  unsigned short* Ximg  = (unsigned short*)(ws + oXimg);
  unsigned short* Xmean = (unsigned short*)(ws + oXmean);
  unsigned short* Xemb  = (unsigned short*)(ws + oXemb);
  unsigned short* X1    = (unsigned short*)(ws + oX1);
  unsigned short* X2    = (unsigned short*)(ws + oX2);
  unsigned short* Xh1   = (unsigned short*)(ws + oXh1);
  unsigned short* Xh2   = (unsigned short*)(ws + oXh2);
  float* c1    = (float*)(ws + oc1);
  float* c2    = (float*)(ws + oc2);
  unsigned short* Xtop  = (unsigned short*)(ws + oXtop);
  unsigned short* Ttopb = (unsigned short*)(ws + oTtopb);
  float* att1  = (float*)(ws + oatt1);
  float* gb1   = (float*)(ws + ogb1);
  float* gemb  = (float*)(ws + ogemb);
  unsigned short* pg    = (unsigned short*)(ws + opg);
  unsigned short* px    = (unsigned short*)(ws + opx);
  unsigned short* padec = (unsigned short*)(ws + opadec);
  unsigned short* Wg1   = (unsigned short*)(ws + oWg1);
  unsigned short* Wg2   = (unsigned short*)(ws + oWg2);
  unsigned short* Wcat  = (unsigned short*)(ws + oWcat);
  unsigned short* Wfcb  = (unsigned short*)(ws + oWfcb);
  unsigned short* Wtopb = (unsigned short*)(ws + oWtopb);

  const long long S4 = 112ll * 4096;   // gate partial slot stride

  hipMemsetAsync(ws + oZERO, 0, zeroBytes, stream);

  // -------- phase A (once) --------
  k_ximg2<<<1600, 256, 0, stream>>>(imgf, Ximg, Xmean);
  k_pack_all<<<53536, 256, 0, stream>>>(W_ih1, W_hh1, W_ih2, W_hh2, W_fc1, W_dec,
                                        W_fc, W_top, Wg1, Wg2, Wcat, Wfcb, Wtopb);
  // lin partials: K=4096 = z2 * (16 chunks * 128)
  gemm_pf<16, false><<<dim3(16, 14, 2), 256, 0, stream>>>(
      Ximg, 4096, W_lt, 4096, 1024, px, 1568ll * 1024, nullptr, 0, 0);
  k_conv<<<100, 512, 0, stream>>>(px, b_lt, convw, convb, Xtop);
  // ttop: K=512 (4 chunks), bf16 out
  gemm_pb<4, false><<<dim3(8, 5, 1), 256, 0, stream>>>(
      Xtop, 512, Wtopb, 512, 512, Ttopb, 0, nullptr, 0, 0);
  // att1 partials: z4 * (8 chunks)
  gemm_pf<8, false><<<dim3(8, 14, 4), 256, 0, stream>>>(
      Ximg, 4096, W_feat, 4096, 512, px, 1568ll * 512, nullptr, 0, 0);
  k_reduce<<<3136, 256, 0, stream>>>(px, 1568ll * 512, 4, b_feat, 511, att1, 1568 * 512);
  k_gw<<<2240, 256, 0, stream>>>(caps, lens, emb, Xemb, out + 10000000, out + 10026000);
  // img_mean panel of W_ih1: z4 * (8 chunks), bf16 partials
  gemm_pf<8, false><<<dim3(64, 1, 4), 256, 0, stream>>>(
      Xmean, 4096, W_ih1 + 1024, 6144, 4096, pg, S4, nullptr, 0, 0);
  k_gbase1<<<1792, 256, 0, stream>>>(pg, b_ih1, b_hh1, gb1);
  // emb panel of W_ih1: K=1024 (8 chunks), direct f32
  gemm_pf<8, true><<<dim3(64, 5, 1), 256, 0, stream>>>(
      Xemb, 1024, W_ih1 + 5120, 6144, 4096, gemb, 0, nullptr, 4096, 560);

  // -------- recurrent steps --------
  for (int t = 0; t < 5; ++t) {
    // gates1 = Wg1 @ [h2|h1prev]: K=2048 = z4 * (4 chunks)
    gemm_pb<4, false><<<dim3(64, 1, 4), 256, 0, stream>>>(
        X1, 2048, Wg1, 2048, 4096, pg, S4, nullptr, 0, 0);
    k_lstm1<<<400, 256, 0, stream>>>(pg, gb1, gemb, t, c1, Xh1, X1, X2);
    // [preds1 | adec] = Xh1 @ Wcat^T: K=1024, direct split epilogue
    gemm_pcat<<<dim3(165, 1, 1), 256, 0, stream>>>(
        Xh1, Wcat, out + 5000000 + t * 10000, b_fc1, padec);
    k_attawe<<<100, 256, 0, stream>>>(att1, padec, b_dec, b_top, Ttopb, W_full, t,
                                      Ximg, X2);
    // gates2 = Wg2 @ [awe|h1|h2prev]: K=6144 = z6 * (8 chunks)
    gemm_pb<8, false><<<dim3(64, 1, 6), 256, 0, stream>>>(
        X2, 6144, Wg2, 6144, 4096, pg, S4, nullptr, 0, 0);
    k_lstm2<<<400, 256, 0, stream>>>(pg, b_ih2, b_hh2, c2, Xh2, X1, X2);
    // preds = Xh2 @ Wfcb^T + b_fc: K=1024, direct f32
    gemm_pb<8, true><<<dim3(157, 1, 1), 256, 0, stream>>>(
        Xh2, 1024, Wfcb, 1024, 10000, out + t * 10000, 0, b_fc, 50000, 100);
  }
}

// Round 8
// 688.582 us; speedup vs baseline: 1.3667x; 1.3667x over previous
//
#include <hip/hip_runtime.h>

typedef __attribute__((ext_vector_type(8))) short short8;
typedef __attribute__((ext_vector_type(4))) short short4v;
typedef __attribute__((ext_vector_type(4))) float f32x4;

__device__ __forceinline__ unsigned short f2bf(float f) {
  unsigned int u = __float_as_uint(f);
  u += 0x7fffu + ((u >> 16) & 1u);   // RNE round to bf16
  return (unsigned short)(u >> 16);
}
__device__ __forceinline__ float bf2f(unsigned short u) {
  return __uint_as_float(((unsigned int)u) << 16);
}
__device__ __forceinline__ float sigm(float x) { return 1.f / (1.f + expf(-x)); }

// ---------------------------------------------------------------------------
// Skinny GEMM (round-5 proven core): 112(M) x 64(N) per block, K=NKC*256/z.
// X staged to LDS fragment-major (57 KB -> 2 blocks/CU); 8-deep W reg burst.
// ---------------------------------------------------------------------------
template<int NKC>
__global__ __launch_bounds__(256) void gemm_v5(
    const unsigned short* __restrict__ X, int ldx,
    const unsigned short* __restrict__ W, int ldw, int N,
    unsigned short* __restrict__ C, long long slotStride)
{
  __shared__ short8 lds[3584];
  const int tid = threadIdx.x;
  const int lane = tid & 63, wv = tid >> 6;
  const int l16 = lane & 15, kg = (lane >> 4) * 8;
  const int mbase = blockIdx.y * 112;
  const int ncol = blockIdx.x * 64 + wv * 16 + l16;
  const int nrow = (ncol < N) ? ncol : (N - 1);
  const long long k0 = (long long)blockIdx.z * (NKC * 256);
  C += (long long)blockIdx.z * slotStride;

  const unsigned short* wp = W + (size_t)nrow * ldw + kg + k0;
  const unsigned short* xb = X + (size_t)(mbase + l16) * ldx + kg + k0;
  const size_t xrow = (size_t)16 * ldx;

  f32x4 acc[7];
#pragma unroll
  for (int i = 0; i < 7; ++i) acc[i] = (f32x4){0.f, 0.f, 0.f, 0.f};

  for (int kc = 0; kc < NKC; ++kc) {
    if (kc) __syncthreads();
    short8 wbuf[8];
#pragma unroll
    for (int ks = 0; ks < 8; ++ks)
      wbuf[ks] = *(const short8*)(wp + kc * 256 + ks * 32);
    short8 xst[14];
#pragma unroll
    for (int i = 0; i < 14; ++i) {
      const int f = wv + i * 4, mt = f >> 3, ks = f & 7;
      xst[i] = *(const short8*)(xb + (size_t)mt * xrow + kc * 256 + ks * 32);
    }
#pragma unroll
    for (int i = 0; i < 14; ++i) lds[(wv + i * 4) * 64 + lane] = xst[i];
    __syncthreads();
#pragma unroll
    for (int ks = 0; ks < 8; ++ks)
#pragma unroll
      for (int mt = 0; mt < 7; ++mt) {
        short8 a = lds[(mt * 8 + ks) * 64 + lane];
        acc[mt] = __builtin_amdgcn_mfma_f32_16x16x32_bf16(a, wbuf[ks], acc[mt], 0, 0, 0);
      }
  }
  if (ncol < N) {
    const int r0 = (lane >> 4) * 4;
#pragma unroll
    for (int mt = 0; mt < 7; ++mt)
#pragma unroll
      for (int r = 0; r < 4; ++r)
        C[(size_t)(mbase + mt * 16 + r0 + r) * N + ncol] = f2bf(acc[mt][r]);
  }
}

// Same, f32 weights (one-time-use panels), converted in-register.
template<int NKC>
__global__ __launch_bounds__(256) void gemm_v5f(
    const unsigned short* __restrict__ X, int ldx,
    const float* __restrict__ W, int ldw, int N,
    unsigned short* __restrict__ C, long long slotStride)
{
  __shared__ short8 lds[3584];
  const int tid = threadIdx.x;
  const int lane = tid & 63, wv = tid >> 6;
  const int l16 = lane & 15, kg = (lane >> 4) * 8;
  const int mbase = blockIdx.y * 112;
  const int ncol = blockIdx.x * 64 + wv * 16 + l16;
  const int nrow = (ncol < N) ? ncol : (N - 1);
  const long long k0 = (long long)blockIdx.z * (NKC * 256);
  C += (long long)blockIdx.z * slotStride;

  const float* wp = W + (size_t)nrow * ldw + kg + k0;
  const unsigned short* xb = X + (size_t)(mbase + l16) * ldx + kg + k0;
  const size_t xrow = (size_t)16 * ldx;

  f32x4 acc[7];
#pragma unroll
  for (int i = 0; i < 7; ++i) acc[i] = (f32x4){0.f, 0.f, 0.f, 0.f};

  for (int kc = 0; kc < NKC; ++kc) {
    if (kc) __syncthreads();
    float4 wa[8], wb[8];
#pragma unroll
    for (int ks = 0; ks < 8; ++ks) {
      wa[ks] = *(const float4*)(wp + kc * 256 + ks * 32);
      wb[ks] = *(const float4*)(wp + kc * 256 + ks * 32 + 4);
    }
    short8 xst[14];
#pragma unroll
    for (int i = 0; i < 14; ++i) {
      const int f = wv + i * 4, mt = f >> 3, ks = f & 7;
      xst[i] = *(const short8*)(xb + (size_t)mt * xrow + kc * 256 + ks * 32);
    }
#pragma unroll
    for (int i = 0; i < 14; ++i) lds[(wv + i * 4) * 64 + lane] = xst[i];
    __syncthreads();
#pragma unroll
    for (int ks = 0; ks < 8; ++ks) {
      short8 w;
      w[0] = (short)f2bf(wa[ks].x); w[1] = (short)f2bf(wa[ks].y);
      w[2] = (short)f2bf(wa[ks].z); w[3] = (short)f2bf(wa[ks].w);
      w[4] = (short)f2bf(wb[ks].x); w[5] = (short)f2bf(wb[ks].y);
      w[6] = (short)f2bf(wb[ks].z); w[7] = (short)f2bf(wb[ks].w);
#pragma unroll
      for (int mt = 0; mt < 7; ++mt) {
        short8 a = lds[(mt * 8 + ks) * 64 + lane];
        acc[mt] = __builtin_amdgcn_mfma_f32_16x16x32_bf16(a, w, acc[mt], 0, 0, 0);
      }
    }
  }
  if (ncol < N) {
    const int r0 = (lane >> 4) * 4;
#pragma unroll
    for (int mt = 0; mt < 7; ++mt)
#pragma unroll
      for (int r = 0; r < 4; ++r)
        C[(size_t)(mbase + mt * 16 + r0 + r) * N + ncol] = f2bf(acc[mt][r]);
  }
}

// -------- fused weight pack: Wg1, Wg2, Wcat=[Wfc1;Wdec], Wfcb, Wtopb --------
__global__ __launch_bounds__(256) void k_pack_all(
    const float* __restrict__ Wih1, const float* __restrict__ Whh1,
    const float* __restrict__ Wih2, const float* __restrict__ Whh2,
    const float* __restrict__ Wfc1, const float* __restrict__ Wdec,
    const float* __restrict__ Wfc,  const float* __restrict__ Wtop,
    unsigned short* __restrict__ Wg1, unsigned short* __restrict__ Wg2,
    unsigned short* __restrict__ Wcat, unsigned short* __restrict__ Wfcb,
    unsigned short* __restrict__ Wtopb)
{
  int i = blockIdx.x * 256 + threadIdx.x;            // 13,705,216 vec4 total
  float4 v; unsigned short* dst; long long di;
  if (i < 2097152) {                                  // Wg1 = [Wih1.h2 | Whh1]
    int row = i >> 9, c4 = i & 511;
    const float* s = (c4 < 256) ? Wih1 + (size_t)row * 6144 + c4 * 4
                                : Whh1 + (size_t)row * 1024 + (c4 - 256) * 4;
    v = *(const float4*)s; dst = Wg1; di = i;
  } else if (i < 8388608) {                           // Wg2 = [Wih2 | Whh2]
    int j = i - 2097152; int row = j / 1536, c4 = j - row * 1536;
    const float* s = (c4 < 1280) ? Wih2 + (size_t)row * 5120 + c4 * 4
                                 : Whh2 + (size_t)row * 1024 + (c4 - 1280) * 4;
    v = *(const float4*)s; dst = Wg2; di = j;
  } else if (i < 11079680) {                          // Wcat = [Wfc1 ; Wdec]
    int j = i - 8388608; int row = j >> 8, c4 = j & 255;
    const float* s = (row < 10000) ? Wfc1 + (size_t)row * 1024 + c4 * 4
                                   : Wdec + (size_t)(row - 10000) * 1024 + c4 * 4;
    v = *(const float4*)s; dst = Wcat; di = j;
  } else if (i < 13639680) { int j = i - 11079680; v = ((const float4*)Wfc)[j]; dst = Wfcb; di = j; }
  else {                                              // Wtopb 512x512, K-pad
    int j = i - 13639680; if (j >= 65536) return;
    int n = j >> 7, c4 = j & 127;
    v = (c4 < 125) ? *(const float4*)(Wtop + (size_t)n * 500 + c4 * 4)
                   : (float4){0.f, 0.f, 0.f, 0.f};
    dst = Wtopb; di = j;
  }
  short4v o; o[0] = (short)f2bf(v.x); o[1] = (short)f2bf(v.y);
  o[2] = (short)f2bf(v.z); o[3] = (short)f2bf(v.w);
  ((short4v*)dst)[di] = o;
}

// --------------------------- phase-A helper kernels ------------------------
__global__ __launch_bounds__(256) void k_ximg2(const float* __restrict__ img,
    unsigned short* __restrict__ Ximg, unsigned short* __restrict__ Xmean) {
  int idx = blockIdx.x * 256 + threadIdx.x;          // 100*4096
  int b = idx >> 12, f = idx & 4095;
  float s = 0.f;
#pragma unroll
  for (int r = 0; r < 15; ++r) {
    float v = img[((size_t)(b * 15 + r) << 12) + f];
    s += v;
    Ximg[((size_t)(b * 15 + r) << 12) + f] = f2bf(v);
  }
  Xmean[((size_t)b << 12) + f] = f2bf(s * (1.f / 15.f));
}

__global__ __launch_bounds__(256) void k_reduce(const unsigned short* __restrict__ P,
    long long ss, int nslots, const float* __restrict__ bias, int colmask,
    float* __restrict__ out, int total) {
  int idx = blockIdx.x * 256 + threadIdx.x;
  if (idx >= total) return;
  float s = bias ? bias[idx & colmask] : 0.f;
  for (int sl = 0; sl < nslots; ++sl) s += bf2f(P[(size_t)sl * ss + idx]);
  out[idx] = s;
}

// conv: fused lin split-K reduce (8 bf16 slots) + direct bf16 Xtop write
__global__ __launch_bounds__(512) void k_conv(const unsigned short* __restrict__ px,
    const float* __restrict__ blt, const float* __restrict__ cw,
    const float* __restrict__ cb, unsigned short* __restrict__ Xtop) {
  int b = blockIdx.x;
  __shared__ float L[15 * 1024];
  for (int i = threadIdx.x; i < 15 * 1024; i += 512) {
    float s = blt[i & 1023];
#pragma unroll
    for (int sl = 0; sl < 8; ++sl)
      s += bf2f(px[(size_t)sl * 1605632 + (size_t)b * 15360 + i]);
    L[i] = s;
  }
  __syncthreads();
  for (int idx = threadIdx.x; idx < 2500; idx += 512) {
    int tt = idx / 500, w = idx - tt * 500;
    float s = cb[tt];
    for (int kh = 0; kh < 15; ++kh) {
      const float* lr = &L[kh * 1024 + 2 * w];
      const float* wr = &cw[(tt * 15 + kh) * 26];
#pragma unroll
      for (int kw = 0; kw < 26; ++kw) s += lr[kw] * wr[kw];
    }
    Xtop[((size_t)(b * 5 + tt)) * 512 + w] = f2bf(s);
  }
}

// word gather + caps/lens outputs, one dispatch
__global__ __launch_bounds__(256) void k_gw(const int* __restrict__ caps,
    const int* __restrict__ lens, const float* __restrict__ emb,
    unsigned short* __restrict__ Xemb, float* __restrict__ out2,
    float* __restrict__ out3) {
  int idx = blockIdx.x * 256 + threadIdx.x;          // 560*1024
  int bt = idx >> 10, e = idx & 1023;
  if (bt < 500) {
    int w = caps[bt * 52 + lens[bt] - 1];
    Xemb[idx] = f2bf(emb[(size_t)w * 1024 + e]);
  } else if (bt < 560) Xemb[idx] = 0;
  if (idx < 26000) out2[idx] = (float)caps[idx];
  if (idx < 500) out3[idx] = (float)(lens[idx] - 1);
}

__global__ __launch_bounds__(256) void k_gbase1(const unsigned short* __restrict__ P,
    const float* __restrict__ bih, const float* __restrict__ bhh,
    float* __restrict__ gb) {
  int idx = blockIdx.x * 256 + threadIdx.x;          // 112*4096
  int m = idx >> 12, n = idx & 4095;
  float s = bih[n] + bhh[n];
#pragma unroll
  for (int sl = 0; sl < 8; ++sl) s += bf2f(P[((size_t)sl * 112 + m) * 4096 + n]);
  gb[idx] = s;
}

// ------------------------------ per-step kernels ---------------------------
__global__ __launch_bounds__(256) void k_lstm1(const unsigned short* __restrict__ P,
    const float* __restrict__ gb1, const float* __restrict__ gemb, int t,
    float* __restrict__ c1, unsigned short* __restrict__ Xh1,
    unsigned short* __restrict__ X1, unsigned short* __restrict__ X2) {
  int idx = blockIdx.x * 256 + threadIdx.x;          // 100*1024
  int b = idx >> 10, j = idx & 1023;
  float g[4];
#pragma unroll
  for (int x = 0; x < 4; ++x) {
    int col = (x << 10) + j;
    float s = gb1[b * 4096 + col] + gemb[((size_t)b * 5 + t) * 4096 + col];
#pragma unroll
    for (int sl = 0; sl < 8; ++sl) s += bf2f(P[((size_t)sl * 112 + b) * 4096 + col]);
    g[x] = s;
  }
  float c = sigm(g[1]) * c1[idx] + sigm(g[0]) * tanhf(g[2]);
  float h = sigm(g[3]) * tanhf(c);
  c1[idx] = c;
  unsigned short hb = f2bf(h);
  Xh1[idx] = hb;
  X1[b * 2048 + 1024 + j] = hb;
  X2[(size_t)b * 6144 + 4096 + j] = hb;
}

// merged: blocks 0..99 = attention+softmax+awe; blocks 100.. = preds1 epilogue
__global__ __launch_bounds__(256) void k_attpred(const float* __restrict__ att1,
    const unsigned short* __restrict__ px, const float* __restrict__ bdec,
    const float* __restrict__ btop, const unsigned short* __restrict__ ttopb,
    const float* __restrict__ wfull, int t,
    const unsigned short* __restrict__ Ximg, unsigned short* __restrict__ X2,
    const float* __restrict__ bfc1, float* __restrict__ outp) {
  if (blockIdx.x >= 100) {
    int idx = (blockIdx.x - 100) * 256 + threadIdx.x;   // 100*10000
    if (idx >= 1000000) return;
    int b = idx / 10000, v = idx - b * 10000;
    outp[((size_t)b * 5 + t) * 10000 + v] = bfc1[v]
        + bf2f(px[(size_t)b * 10512 + v])         + bf2f(px[(size_t)(112 + b) * 10512 + v])
        + bf2f(px[(size_t)(224 + b) * 10512 + v]) + bf2f(px[(size_t)(336 + b) * 10512 + v]);
    return;
  }
  int b = blockIdx.x;
  int tid = threadIdx.x;
  int r = tid & 15, ch = tid >> 4;                   // 15 regions x 16 chunks
  __shared__ float sp[16][17];
  __shared__ float al[16];
  float s = 0.f;
  if (r < 15) {
    const float* a1 = att1 + ((size_t)b * 15 + r) * 512;
    const unsigned short* tp = ttopb + ((size_t)b * 5 + t) * 512;
#pragma unroll
    for (int j = 0; j < 32; ++j) {
      int n = ch * 32 + j;
      float ad = bdec[n] + btop[n]
               + bf2f(px[((size_t)0 * 112 + b) * 10512 + 10000 + n])
               + bf2f(px[((size_t)1 * 112 + b) * 10512 + 10000 + n])
               + bf2f(px[((size_t)2 * 112 + b) * 10512 + 10000 + n])
               + bf2f(px[((size_t)3 * 112 + b) * 10512 + 10000 + n]);
      float v = a1[n] + ad + bf2f(tp[n]);
      s += fmaxf(v, 0.f) * wfull[n];
    }
  }
  sp[r][ch] = s;
  __syncthreads();
  if (tid == 0) {
    float sc[15];
    float m = -1e30f;
    for (int rr = 0; rr < 15; ++rr) {
      float x = 0.f;
      for (int cc = 0; cc < 16; ++cc) x += sp[rr][cc];
      sc[rr] = x; m = fmaxf(m, x);
    }
    float sum = 0.f;
    for (int rr = 0; rr < 15; ++rr) { sc[rr] = expf(sc[rr] - m); sum += sc[rr]; }
    float inv = 1.f / sum;
    for (int rr = 0; rr < 15; ++rr) al[rr] = sc[rr] * inv;
  }
  __syncthreads();
  for (int f = tid; f < 4096; f += 256) {
    float s2 = 0.f;
#pragma unroll
    for (int rr = 0; rr < 15; ++rr)
      s2 += al[rr] * bf2f(Ximg[((size_t)b * 15 + rr) * 4096 + f]);
    X2[(size_t)b * 6144 + f] = f2bf(s2);
  }
}

__global__ __launch_bounds__(256) void k_lstm2(const unsigned short* __restrict__ P,
    const float* __restrict__ bih, const float* __restrict__ bhh,
    float* __restrict__ c2, unsigned short* __restrict__ Xh2,
    unsigned short* __restrict__ X1, unsigned short* __restrict__ X2) {
  int idx = blockIdx.x * 256 + threadIdx.x;          // 100*1024
  int b = idx >> 10, j = idx & 1023;
  float g[4];
#pragma unroll
  for (int x = 0; x < 4; ++x) {
    int col = (x << 10) + j;
    float s = bih[col] + bhh[col];
#pragma unroll
    for (int sl = 0; sl < 12; ++sl) s += bf2f(P[((size_t)sl * 112 + b) * 4096 + col]);
    g[x] = s;
  }
  float c = sigm(g[1]) * c2[idx] + sigm(g[0]) * tanhf(g[2]);
  float h = sigm(g[3]) * tanhf(c);
  c2[idx] = c;
  unsigned short hb = f2bf(h);
  Xh2[idx] = hb;
  X1[b * 2048 + j] = hb;
  X2[(size_t)b * 6144 + 5120 + j] = hb;
}

__global__ __launch_bounds__(256) void k_eppred(const unsigned short* __restrict__ P,
    const float* __restrict__ bias, float* __restrict__ outp, int t, int ldp) {
  int idx = blockIdx.x * 256 + threadIdx.x;          // 100*10000
  if (idx >= 1000000) return;
  int b = idx / 10000, v = idx - b * 10000;
  outp[((size_t)b * 5 + t) * 10000 + v] = bias[v]
      + bf2f(P[(size_t)b * ldp + v])         + bf2f(P[(size_t)(112 + b) * ldp + v])
      + bf2f(P[(size_t)(224 + b) * ldp + v]) + bf2f(P[(size_t)(336 + b) * ldp + v]);
}

// ---------------------------------------------------------------------------
extern "C" void kernel_launch(void* const* d_in, const int* in_sizes, int n_in,
                              void* d_out, int out_size, void* d_ws, size_t ws_size,
                              hipStream_t stream) {
  (void)in_sizes; (void)n_in; (void)out_size;
  const float* imgf  = (const float*)d_in[0];
  const int*   caps  = (const int*)d_in[1];
  const int*   lens  = (const int*)d_in[2];
  const float* W_lt  = (const float*)d_in[3];
  const float* b_lt  = (const float*)d_in[4];
  const float* convw = (const float*)d_in[5];
  const float* convb = (const float*)d_in[6];
  const float* W_feat = (const float*)d_in[7];
  const float* b_feat = (const float*)d_in[8];
  const float* W_dec = (const float*)d_in[9];
  const float* b_dec = (const float*)d_in[10];
  const float* W_top = (const float*)d_in[11];
  const float* b_top = (const float*)d_in[12];
  const float* W_full = (const float*)d_in[13];
  const float* b_full = (const float*)d_in[14];  (void)b_full;  // cancels in softmax
  const float* emb   = (const float*)d_in[15];
  const float* W_ih1 = (const float*)d_in[16];
  const float* W_hh1 = (const float*)d_in[17];
  const float* b_ih1 = (const float*)d_in[18];
  const float* b_hh1 = (const float*)d_in[19];
  const float* W_ih2 = (const float*)d_in[20];
  const float* W_hh2 = (const float*)d_in[21];
  const float* b_ih2 = (const float*)d_in[22];
  const float* b_hh2 = (const float*)d_in[23];
  const float* W_fc1 = (const float*)d_in[24];
  const float* b_fc1 = (const float*)d_in[25];
  const float* W_fc  = (const float*)d_in[26];
  const float* b_fc  = (const float*)d_in[27];
  float* out = (float*)d_out;

  char* ws = (char*)d_ws;
  size_t off = 0;
  auto alloc = [&](size_t bytes) -> size_t {
    size_t o = off; off = (off + bytes + 255) & ~(size_t)255; return o;
  };
  const size_t oZERO  = off;                         // ---- zero block start
  const size_t oXimg  = alloc(1568ull * 4096 * 2);
  const size_t oXmean = alloc(112ull * 4096 * 2);
  const size_t oX1    = alloc(112ull * 2048 * 2);    // [h2 | h1] bf16
  const size_t oX2    = alloc(112ull * 6144 * 2);    // [awe | h1 | h2prev] bf16
  const size_t oXh1   = alloc(112ull * 1024 * 2);
  const size_t oXh2   = alloc(112ull * 1024 * 2);
  const size_t oc1    = alloc(100ull * 1024 * 4);
  const size_t oc2    = alloc(100ull * 1024 * 4);
  const size_t oXtop  = alloc(560ull * 512 * 2);
  const size_t zeroBytes = off - oZERO;              // ---- zero block end
  const size_t oXemb  = alloc(560ull * 1024 * 2);
  const size_t oTtopb = alloc(560ull * 512 * 2);
  const size_t oatt1  = alloc(1568ull * 512 * 4);
  const size_t ogb1   = alloc(112ull * 4096 * 4);
  const size_t ogemb  = alloc(560ull * 4096 * 4);
  const size_t opg    = alloc(12ull * 112 * 4096 * 2);  // gate partials (bf16)
  const size_t opx    = alloc(8ull * 1568 * 1024 * 2);  // shared partials (bf16)
  const size_t oWg1   = alloc(4096ull * 2048 * 2);      // [Wih1.h2 | Whh1]
  const size_t oWg2   = alloc(4096ull * 6144 * 2);      // [Wih2 | Whh2]
  const size_t oWcat  = alloc(10512ull * 1024 * 2);     // [W_fc1 ; W_dec]
  const size_t oWfcb  = alloc(10000ull * 1024 * 2);
  const size_t oWtopb = alloc(512ull * 512 * 2);
  if (ws_size < off) return;  // insufficient scratch — loud fail

  unsigned short* Ximg  = (unsigned short*)(ws + oXimg);
  unsigned short* Xmean = (unsigned short*)(ws + oXmean);
  unsigned short* Xemb  = (unsigned short*)(ws + oXemb);
  unsigned short* X1    = (unsigned short*)(ws + oX1);
  unsigned short* X2    = (unsigned short*)(ws + oX2);
  unsigned short* Xh1   = (unsigned short*)(ws + oXh1);
  unsigned short* Xh2   = (unsigned short*)(ws + oXh2);
  float* c1    = (float*)(ws + oc1);
  float* c2    = (float*)(ws + oc2);
  unsigned short* Xtop  = (unsigned short*)(ws + oXtop);
  unsigned short* Ttopb = (unsigned short*)(ws + oTtopb);
  float* att1  = (float*)(ws + oatt1);
  float* gb1   = (float*)(ws + ogb1);
  float* gemb  = (float*)(ws + ogemb);
  unsigned short* pg    = (unsigned short*)(ws + opg);
  unsigned short* px    = (unsigned short*)(ws + opx);
  unsigned short* Wg1   = (unsigned short*)(ws + oWg1);
  unsigned short* Wg2   = (unsigned short*)(ws + oWg2);
  unsigned short* Wcat  = (unsigned short*)(ws + oWcat);
  unsigned short* Wfcb  = (unsigned short*)(ws + oWfcb);
  unsigned short* Wtopb = (unsigned short*)(ws + oWtopb);

  const long long S4  = 112ll * 4096;    // gate partial slot stride
  const long long SP1 = 112ll * 10512;   // cat partial slot stride
  const long long SP  = 112ll * 10000;   // preds partial slot stride

  hipMemsetAsync(ws + oZERO, 0, zeroBytes, stream);

  // -------- phase A (once) --------
  k_ximg2<<<1600, 256, 0, stream>>>(imgf, Ximg, Xmean);
  k_pack_all<<<53536, 256, 0, stream>>>(W_ih1, W_hh1, W_ih2, W_hh2, W_fc1, W_dec,
                                        W_fc, W_top, Wg1, Wg2, Wcat, Wfcb, Wtopb);
  // lin partials: f32 W direct, K=4096 = z8 * (2 chunks * 256)
  gemm_v5f<2><<<dim3(16, 14, 8), 256, 0, stream>>>(Ximg, 4096, W_lt, 4096, 1024,
                                                   px, 1568ll * 1024);
  k_conv<<<100, 512, 0, stream>>>(px, b_lt, convw, convb, Xtop);
  // ttop: K=512, bf16 out
  gemm_v5<2><<<dim3(8, 5, 1), 256, 0, stream>>>(Xtop, 512, Wtopb, 512, 512, Ttopb, 0);
  // att1 partials: f32 W direct, z8 * (2 chunks)
  gemm_v5f<2><<<dim3(8, 14, 8), 256, 0, stream>>>(Ximg, 4096, W_feat, 4096, 512,
                                                  px, 1568ll * 512);
  k_reduce<<<3136, 256, 0, stream>>>(px, 1568ll * 512, 8, b_feat, 511, att1, 1568 * 512);
  k_gw<<<2240, 256, 0, stream>>>(caps, lens, emb, Xemb, out + 10000000, out + 10026000);
  // img_mean panel of W_ih1 (f32, one-time): z8 * (2 chunks)
  gemm_v5f<2><<<dim3(64, 1, 8), 256, 0, stream>>>(Xmean, 4096, W_ih1 + 1024, 6144, 4096,
                                                  pg, S4);
  k_gbase1<<<1792, 256, 0, stream>>>(pg, b_ih1, b_hh1, gb1);
  // emb panel of W_ih1 (f32, one-time): all 5 steps, K=1024 = z4 * 256
  gemm_v5f<1><<<dim3(64, 5, 4), 256, 0, stream>>>(Xemb, 1024, W_ih1 + 5120, 6144, 4096,
                                                  px, 560ll * 4096);
  k_reduce<<<8960, 256, 0, stream>>>(px, 560ll * 4096, 4, nullptr, 4095, gemb, 560 * 4096);

  // -------- recurrent steps --------
  for (int t = 0; t < 5; ++t) {
    // gates1 = Wg1 @ [h2|h1prev]: K=2048 = z8 * 256
    gemm_v5<1><<<dim3(64, 1, 8), 256, 0, stream>>>(X1, 2048, Wg1, 2048, 4096, pg, S4);
    k_lstm1<<<400, 256, 0, stream>>>(pg, gb1, gemb, t, c1, Xh1, X1, X2);
    // [preds1 | adec] = Xh1 @ Wcat^T: N=10512, K=1024 = z4 * 256
    gemm_v5<1><<<dim3(165, 1, 4), 256, 0, stream>>>(Xh1, 1024, Wcat, 1024, 10512, px, SP1);
    k_attpred<<<4007, 256, 0, stream>>>(att1, px, b_dec, b_top, Ttopb, W_full, t,
                                        Ximg, X2, b_fc1, out + 5000000);
    // gates2 = Wg2 @ [awe|h1|h2prev]: K=6144 = z12 * (2 chunks * 256)
    gemm_v5<2><<<dim3(64, 1, 12), 256, 0, stream>>>(X2, 6144, Wg2, 6144, 4096, pg, S4);
    k_lstm2<<<400, 256, 0, stream>>>(pg, b_ih2, b_hh2, c2, Xh2, X1, X2);
    // preds = Xh2 @ Wfcb^T: K=1024 = z4 * 256
    gemm_v5<1><<<dim3(157, 1, 4), 256, 0, stream>>>(Xh2, 1024, Wfcb, 1024, 10000, px, SP);
    k_eppred<<<3907, 256, 0, stream>>>(px, b_fc, out, t, 10000);
  }
}